// Round 7
// baseline (252.713 us; speedup 1.0000x reference)
//
#include <hip/hip_runtime.h>
#include <hip/hip_cooperative_groups.h>
#include <math.h>

namespace cg = cooperative_groups;

#define QN 131072
#define NF 9
#define NH 64
#define NO 128
#define NBLK 512          // 256 queries per block, 2 tiles of 128

using v8s = __attribute__((ext_vector_type(8))) short;
using v4f = __attribute__((ext_vector_type(4))) float;

__device__ __forceinline__ unsigned short f2bf(float x) {
  unsigned u = __float_as_uint(x);
  unsigned r = u + 0x7fffu + ((u >> 16) & 1u);   // RNE
  return (unsigned short)(r >> 16);
}

// =====================================================================
// Shared device helpers (used by both coop and fallback paths)
// =====================================================================
__device__ __forceinline__ void eig3(float a00, float a01, float a02,
                                     float a11, float a12, float a22,
                                     float& l0, float& l1, float& l2) {
  float p1 = a01*a01 + a02*a02 + a12*a12;
  float qm = (a00 + a11 + a22) * (1.0f/3.0f);
  float b00 = a00 - qm, b11 = a11 - qm, b22 = a22 - qm;
  float p2 = b00*b00 + b11*b11 + b22*b22 + 2.0f*p1;
  if (p2 < 1e-12f) {
    l0 = l1 = l2 = qm;
  } else {
    float p = sqrtf(p2 * (1.0f/6.0f));
    float ip2 = 1.0f / p;
    float c00 = b00*ip2, c11 = b11*ip2, c22 = b22*ip2;
    float c01 = a01*ip2, c02 = a02*ip2, c12 = a12*ip2;
    float det = c00*(c11*c22 - c12*c12)
              - c01*(c01*c22 - c12*c02)
              + c02*(c01*c12 - c11*c02);
    float r = fminf(1.0f, fmaxf(-1.0f, 0.5f*det));
    float phi = acosf(r) * (1.0f/3.0f);
    float tp = 2.0f * p;
    l0 = qm + tp * __cosf(phi);
    l2 = qm + tp * __cosf(phi + 2.0943951023931953f);
    l1 = 3.0f*qm - l0 - l2;
  }
}

// computes ft[9] for query q given 2-thread split j in {0,1}; both lanes of
// the pair end with identical ft.
__device__ __forceinline__ void stat_query(const float4* __restrict__ g4,
                                           const float* __restrict__ lq,
                                           const int* __restrict__ nidx,
                                           const int* __restrict__ rsplit,
                                           int q, int j, float* ft) {
  const int s = rsplit[q];
  const int cnt = rsplit[q+1] - s;     // uniform 32 by construction

  const int* ip = nidx + s + j*16;
  int4 a0 = *(const int4*)(ip     );
  int4 a1 = *(const int4*)(ip +  4);
  int4 a2 = *(const int4*)(ip +  8);
  int4 a3 = *(const int4*)(ip + 12);

  const float qx = lq[q*3+0], qy = lq[q*3+1], qz = lq[q*3+2];

  float sx=0.f, sy=0.f, sz=0.f;
  float sxx=0.f, sxy=0.f, sxz=0.f, syy=0.f, syz=0.f, szz=0.f;
  float sd=0.f, sd2=0.f;

  int idsA[8] = {a0.x,a0.y,a0.z,a0.w, a1.x,a1.y,a1.z,a1.w};
  int idsB[8] = {a2.x,a2.y,a2.z,a2.w, a3.x,a3.y,a3.z,a3.w};
  float4 P[8];
#pragma unroll
  for (int m = 0; m < 8; ++m) P[m] = g4[idsA[m]];
#pragma unroll
  for (int m = 0; m < 8; ++m) {
    float4 p = P[m];
    sx += p.x; sy += p.y; sz += p.z;
    sxx = fmaf(p.x,p.x,sxx); sxy = fmaf(p.x,p.y,sxy); sxz = fmaf(p.x,p.z,sxz);
    syy = fmaf(p.y,p.y,syy); syz = fmaf(p.y,p.z,syz); szz = fmaf(p.z,p.z,szz);
    float dx = p.x-qx, dy = p.y-qy, dz = p.z-qz;
    float dd = fmaf(dx,dx,fmaf(dy,dy,dz*dz));
    sd2 += dd; sd += sqrtf(dd);
  }
#pragma unroll
  for (int m = 0; m < 8; ++m) P[m] = g4[idsB[m]];
#pragma unroll
  for (int m = 0; m < 8; ++m) {
    float4 p = P[m];
    sx += p.x; sy += p.y; sz += p.z;
    sxx = fmaf(p.x,p.x,sxx); sxy = fmaf(p.x,p.y,sxy); sxz = fmaf(p.x,p.z,sxz);
    syy = fmaf(p.y,p.y,syy); syz = fmaf(p.y,p.z,syz); szz = fmaf(p.z,p.z,szz);
    float dx = p.x-qx, dy = p.y-qy, dz = p.z-qz;
    float dd = fmaf(dx,dx,fmaf(dy,dy,dz*dz));
    sd2 += dd; sd += sqrtf(dd);
  }

  sx  += __shfl_xor(sx,  1);
  sy  += __shfl_xor(sy,  1);
  sz  += __shfl_xor(sz,  1);
  sxx += __shfl_xor(sxx, 1);
  sxy += __shfl_xor(sxy, 1);
  sxz += __shfl_xor(sxz, 1);
  syy += __shfl_xor(syy, 1);
  syz += __shfl_xor(syz, 1);
  szz += __shfl_xor(szz, 1);
  sd  += __shfl_xor(sd,  1);
  sd2 += __shfl_xor(sd2, 1);

  float cntf = (float)cnt;
  float denom = fmaxf(cntf, 1.0f);
  float inv = 1.0f / denom;
  float Davg = sd * inv;
  float Dvar = fmaxf(sd2 * inv - Davg*Davg, 0.0f);
  float cx = sx*inv, cy = sy*inv, cz = sz*inv;

  float l0, l1, l2;
  eig3(sxx*inv - cx*cx, sxy*inv - cx*cy, sxz*inv - cx*cz,
       syy*inv - cy*cy, syz*inv - cy*cz, szz*inv - cz*cz, l0, l1, l2);

  if (cntf > 0.f) {
    ft[0] = cntf; ft[1] = Davg; ft[2] = Dvar;
    ft[3] = cx - qx; ft[4] = cy - qy; ft[5] = cz - qz;
    ft[6] = l0; ft[7] = l1; ft[8] = l2;
  } else {
#pragma unroll
    for (int f = 0; f < NF; ++f) ft[f] = 0.f;
  }
}

// =====================================================================
// Cooperative single-kernel path: 512 blocks x 256 thr, 256 queries/block
// =====================================================================
__global__ __launch_bounds__(256, 2)
void fused_kernel(const float* __restrict__ geom,
                  const float* __restrict__ lq,
                  const int* __restrict__ nidx,
                  const int* __restrict__ rsplit,
                  const float* __restrict__ W1,
                  const float* __restrict__ b1,
                  const float* __restrict__ W2,
                  const float* __restrict__ b2,
                  float4* __restrict__ g4,
                  unsigned short* __restrict__ w2f,
                  float* __restrict__ acc,
                  float* __restrict__ out,
                  int nn)
{
  __shared__ __align__(16) unsigned short ldsA[8*2*64*8]; // 16 KB, reused per tile
  __shared__ float sfeat[256][NF];                        // 9.2 KB
  __shared__ float sW1[NF*NH];
  __shared__ float sb1[NH];
  __shared__ float sb2[NO];
  __shared__ float sacc[4][2*NF];
  __shared__ float ssc[NF], sbi[NF];

  cg::grid_group grid = cg::this_grid();
  const int t = threadIdx.x;
  const int b = blockIdx.x;
  const int wave = t >> 6;
  const int lane = t & 63;

  // ---- prologue: pad g4 (grid-stride), block0 builds w2f + zeros acc ----
  for (int gt = b*256 + t; gt < nn; gt += NBLK*256) {
    const float* p = geom + (size_t)gt * 3;
    g4[gt] = make_float4(p[0], p[1], p[2], 0.f);
  }
  if (b == 0) {
    if (t < 2*NF) acc[t] = 0.f;
#pragma unroll
    for (int grp = 0; grp < 8; ++grp) {
      int gi = grp*256 + t;          // [0, 2048)
      int l  = gi & 63;
      int ot = (gi >> 6) & 7;
      int kt = (gi >> 9) & 1;
      int col  = ot*16 + (l & 15);
      int rowb = kt*32 + (l >> 4)*8;
      uint pk[4];
#pragma unroll
      for (int jj = 0; jj < 4; ++jj) {
        uint lo = f2bf(W2[(rowb + 2*jj    )*NO + col]);
        uint hi = f2bf(W2[(rowb + 2*jj + 1)*NO + col]);
        pk[jj] = lo | (hi << 16);
      }
      *(uint4*)&w2f[(size_t)gi*8] = make_uint4(pk[0], pk[1], pk[2], pk[3]);
    }
  }
  for (int i = t; i < NF*NH; i += 256) sW1[i] = W1[i];
  if (t < NH) sb1[t] = b1[t];
  if (t >= 64 && t < 64+NO) sb2[t-64] = b2[t-64];

  grid.sync();

  // ---- stats: two tiles of 128 queries ----
#pragma unroll
  for (int tt = 0; tt < 2; ++tt) {
    const int j  = t & 1;
    const int ql = t >> 1;
    const int q  = b*256 + tt*128 + ql;

    float ft[NF];
    stat_query(g4, lq, nidx, rsplit, q, j, ft);

    if (j == 0) {
#pragma unroll
      for (int f = 0; f < NF; ++f) sfeat[tt*128 + ql][f] = ft[f];
    }

    // xor-orbit reduction (even lanes hold the wave's 32 distinct queries)
#pragma unroll
    for (int f = 0; f < NF; ++f) {
      float s1 = ft[f];
      float s2 = ft[f]*ft[f];
#pragma unroll
      for (int msk = 2; msk < 64; msk <<= 1) {
        s1 += __shfl_xor(s1, msk);
        s2 += __shfl_xor(s2, msk);
      }
      if (lane == 0) { sacc[wave][f] = s1; sacc[wave][NF+f] = s2; }
    }
    __syncthreads();
    if (t < 2*NF) {
      float ssum = sacc[0][t] + sacc[1][t] + sacc[2][t] + sacc[3][t];
      atomicAdd(&acc[t], ssum);
    }
    __syncthreads();   // protect sacc before next tile overwrites
  }

  grid.sync();

  // ---- finalize: scale/bias from global acc ----
  if (t >= 192 && t < 192+NF) {
    int f = t - 192;
    double s = (double)acc[f], s2 = (double)acc[NF+f];
    const double Qd = (double)QN;
    double mean = s / Qd;
    double var = fmax((s2 - s*s/Qd) / (Qd - 1.0), 0.0);
    double sdv = sqrt(var);
    if (sdv < 1e-6) sdv = 1.0;
    double iscl = 1.0 / sdv;
    ssc[f] = (float)iscl;
    sbi[f] = (float)(-mean * iscl);
  }
  __syncthreads();

  // B-fragments into registers (coalesced 16B/lane)
  v8s B00 = ((const v8s*)w2f)[(0*8 + 2*wave    )*64 + lane];
  v8s B01 = ((const v8s*)w2f)[(0*8 + 2*wave + 1)*64 + lane];
  v8s B10 = ((const v8s*)w2f)[(1*8 + 2*wave    )*64 + lane];
  v8s B11 = ((const v8s*)w2f)[(1*8 + 2*wave + 1)*64 + lane];

  // ---- MLP: two tiles ----
#pragma unroll
  for (int tt = 0; tt < 2; ++tt) {
    // phase 1: h = relu(feat@W1+b1) -> A-frags in ldsA
#pragma unroll
    for (int pass = 0; pass < 4; ++pass) {
      int item = pass*256 + t;
      int q  = item & 127;
      int kc = item >> 7;
      float fv[NF];
#pragma unroll
      for (int k = 0; k < NF; ++k)
        fv[k] = fmaf(sfeat[tt*128 + q][k], ssc[k], sbi[k]);

      float h[8];
#pragma unroll
      for (int jj = 0; jj < 8; ++jj) h[jj] = sb1[kc*8 + jj];
#pragma unroll
      for (int k = 0; k < NF; ++k) {
        float fk = fv[k];
#pragma unroll
        for (int jj = 0; jj < 8; ++jj)
          h[jj] = fmaf(fk, sW1[k*NH + kc*8 + jj], h[jj]);
      }
      uint pk[4];
#pragma unroll
      for (int jj = 0; jj < 4; ++jj) {
        uint lo = f2bf(fmaxf(h[2*jj  ], 0.f));
        uint hi = f2bf(fmaxf(h[2*jj+1], 0.f));
        pk[jj] = lo | (hi << 16);
      }
      int base = ((((q >> 4)*2 + (kc >> 2))*64) + (q & 15) + 16*(kc & 3)) * 8;
      *(uint4*)&ldsA[base] = make_uint4(pk[0], pk[1], pk[2], pk[3]);
    }
    __syncthreads();

    // phase 2: MFMA + store
    {
      const int qbase = b*256 + tt*128;
      const int col = lane & 15;
      const int rb  = (lane >> 4) * 4;
      const int o0 = (2*wave    )*16 + col;
      const int o1 = (2*wave + 1)*16 + col;
      const float b2a = sb2[o0];
      const float b2b = sb2[o1];

#pragma unroll
      for (int qt = 0; qt < 8; ++qt) {
        v8s A0 = *(v8s*)&ldsA[((qt*2 + 0)*64 + lane)*8];
        v8s A1 = *(v8s*)&ldsA[((qt*2 + 1)*64 + lane)*8];
        v4f c0 = {0.f, 0.f, 0.f, 0.f};
        v4f c1 = {0.f, 0.f, 0.f, 0.f};
        c0 = __builtin_amdgcn_mfma_f32_16x16x32_bf16(A0, B00, c0, 0, 0, 0);
        c0 = __builtin_amdgcn_mfma_f32_16x16x32_bf16(A1, B10, c0, 0, 0, 0);
        c1 = __builtin_amdgcn_mfma_f32_16x16x32_bf16(A0, B01, c1, 0, 0, 0);
        c1 = __builtin_amdgcn_mfma_f32_16x16x32_bf16(A1, B11, c1, 0, 0, 0);
#pragma unroll
        for (int r = 0; r < 4; ++r) {
          int gq = qbase + qt*16 + rb + r;
          out[(size_t)gq*NO + o0] = fmaxf(c0[r] + b2a, 0.f);
          out[(size_t)gq*NO + o1] = fmaxf(c1[r] + b2b, 0.f);
        }
      }
    }
    __syncthreads();   // protect ldsA before next tile
  }
}

// =====================================================================
// Fallback 3-kernel path (round-5 verified, 133 us)
// =====================================================================
__global__ __launch_bounds__(256)
void prep_kernel(const float* __restrict__ geom, float4* __restrict__ g4, int nn,
                 int padBlocks,
                 const float* __restrict__ W2, unsigned short* __restrict__ w2f,
                 float* __restrict__ acc)
{
  const int t = threadIdx.x;
  const int b = blockIdx.x;
  if (b == 0 && t < 2*NF) acc[t] = 0.0f;
  if (b < padBlocks) {
    int i = b * 256 + t;
    if (i < nn) {
      const float* p = geom + (size_t)i * 3;
      g4[i] = make_float4(p[0], p[1], p[2], 0.f);
    }
  } else {
    int i = (b - padBlocks) * 256 + t;   // [0, 16384)
    int j  = i & 7;
    int l  = (i >> 3) & 63;
    int ot = (i >> 9) & 7;
    int kt = (i >> 12) & 1;
    int row = kt*32 + (l >> 4)*8 + j;
    int col = ot*16 + (l & 15);
    w2f[i] = f2bf(W2[row*NO + col]);
  }
}

__global__ __launch_bounds__(256)
void stats_kernel(const float4* __restrict__ g4,
                  const float* __restrict__ lq,
                  const int* __restrict__ nidx,
                  const int* __restrict__ rsplit,
                  float* __restrict__ feat,
                  float* __restrict__ acc)
{
  const int t = threadIdx.x;
  const int j = t & 1;
  const int q = blockIdx.x * 128 + (t >> 1);

  float ft[NF];
  stat_query(g4, lq, nidx, rsplit, q, j, ft);

  if (j == 0) {
    float* fp = feat + (size_t)q * 12;
    *(float4*)(fp    ) = make_float4(ft[0], ft[1], ft[2], ft[3]);
    *(float4*)(fp + 4) = make_float4(ft[4], ft[5], ft[6], ft[7]);
    *(float4*)(fp + 8) = make_float4(ft[8], 0.f, 0.f, 0.f);
  }

  __shared__ float sacc[4][2*NF];
  const int wid = t >> 6, lane = t & 63;
#pragma unroll
  for (int f = 0; f < NF; ++f) {
    float s1 = ft[f];
    float s2 = ft[f]*ft[f];
#pragma unroll
    for (int msk = 2; msk < 64; msk <<= 1) {
      s1 += __shfl_xor(s1, msk);
      s2 += __shfl_xor(s2, msk);
    }
    if (lane == 0) { sacc[wid][f] = s1; sacc[wid][NF+f] = s2; }
  }
  __syncthreads();
  if (t < 2*NF) {
    float ssum = sacc[0][t] + sacc[1][t] + sacc[2][t] + sacc[3][t];
    atomicAdd(&acc[t], ssum);
  }
}

__global__ __launch_bounds__(256)
void mlp_kernel(const float* __restrict__ feat,
                const float* __restrict__ acc,
                const float* __restrict__ W1, const float* __restrict__ b1,
                const unsigned short* __restrict__ w2f,
                const float* __restrict__ b2,
                float* __restrict__ out)
{
  __shared__ float sW1[NF*NH];
  __shared__ float sb1[NH];
  __shared__ float sb2[NO];
  __shared__ float ssc[NF], sbi[NF];
  __shared__ __align__(16) unsigned short ldsA[8*2*64*8];
  __shared__ __align__(16) unsigned short ldsB[2*8*64*8];

  const int t = threadIdx.x;
  const int qbase = blockIdx.x * 128;

  for (int i = t; i < NF*NH; i += 256) sW1[i] = W1[i];
  if (t < NH) sb1[t] = b1[t];
  if (t >= 64 && t < 64+NO) sb2[t-64] = b2[t-64];
  for (int i = t; i < 4096; i += 256) ((uint*)ldsB)[i] = ((const uint*)w2f)[i];
  if (t >= 192 && t < 192+NF) {
    int f = t - 192;
    double s = (double)acc[f], s2 = (double)acc[NF+f];
    const double Qd = (double)QN;
    double mean = s / Qd;
    double var = fmax((s2 - s*s/Qd) / (Qd - 1.0), 0.0);
    double sd = sqrt(var);
    if (sd < 1e-6) sd = 1.0;
    double iscl = 1.0 / sd;
    ssc[f] = (float)iscl;
    sbi[f] = (float)(-mean * iscl);
  }
  __syncthreads();

#pragma unroll
  for (int pass = 0; pass < 4; ++pass) {
    int item = pass*256 + t;
    int q  = item & 127;
    int kc = item >> 7;
    const float* fp = feat + (size_t)(qbase + q) * 12;
    float4 f0 = *(const float4*)(fp);
    float4 f1 = *(const float4*)(fp + 4);
    float f8v = fp[8];
    float fv[NF];
    fv[0] = fmaf(f0.x, ssc[0], sbi[0]);
    fv[1] = fmaf(f0.y, ssc[1], sbi[1]);
    fv[2] = fmaf(f0.z, ssc[2], sbi[2]);
    fv[3] = fmaf(f0.w, ssc[3], sbi[3]);
    fv[4] = fmaf(f1.x, ssc[4], sbi[4]);
    fv[5] = fmaf(f1.y, ssc[5], sbi[5]);
    fv[6] = fmaf(f1.z, ssc[6], sbi[6]);
    fv[7] = fmaf(f1.w, ssc[7], sbi[7]);
    fv[8] = fmaf(f8v,  ssc[8], sbi[8]);

    float h[8];
#pragma unroll
    for (int jj = 0; jj < 8; ++jj) h[jj] = sb1[kc*8 + jj];
#pragma unroll
    for (int k = 0; k < NF; ++k) {
      float fk = fv[k];
#pragma unroll
      for (int jj = 0; jj < 8; ++jj)
        h[jj] = fmaf(fk, sW1[k*NH + kc*8 + jj], h[jj]);
    }
    uint pk[4];
#pragma unroll
    for (int jj = 0; jj < 4; ++jj) {
      uint lo = f2bf(fmaxf(h[2*jj  ], 0.f));
      uint hi = f2bf(fmaxf(h[2*jj+1], 0.f));
      pk[jj] = lo | (hi << 16);
    }
    int base = ((((q >> 4)*2 + (kc >> 2))*64) + (q & 15) + 16*(kc & 3)) * 8;
    *(uint4*)&ldsA[base] = make_uint4(pk[0], pk[1], pk[2], pk[3]);
  }
  __syncthreads();

  const int wave = t >> 6;
  const int lane = t & 63;
  const int col  = lane & 15;
  const int rb   = (lane >> 4) * 4;

  v8s B00 = *(v8s*)&ldsB[(((0*8) + 2*wave    )*64 + lane)*8];
  v8s B01 = *(v8s*)&ldsB[(((0*8) + 2*wave + 1)*64 + lane)*8];
  v8s B10 = *(v8s*)&ldsB[(((1*8) + 2*wave    )*64 + lane)*8];
  v8s B11 = *(v8s*)&ldsB[(((1*8) + 2*wave + 1)*64 + lane)*8];

  const int o0 = (2*wave    )*16 + col;
  const int o1 = (2*wave + 1)*16 + col;
  const float b2a = sb2[o0];
  const float b2b = sb2[o1];

#pragma unroll
  for (int qt = 0; qt < 8; ++qt) {
    v8s A0 = *(v8s*)&ldsA[((qt*2 + 0)*64 + lane)*8];
    v8s A1 = *(v8s*)&ldsA[((qt*2 + 1)*64 + lane)*8];
    v4f c0 = {0.f, 0.f, 0.f, 0.f};
    v4f c1 = {0.f, 0.f, 0.f, 0.f};
    c0 = __builtin_amdgcn_mfma_f32_16x16x32_bf16(A0, B00, c0, 0, 0, 0);
    c0 = __builtin_amdgcn_mfma_f32_16x16x32_bf16(A1, B10, c0, 0, 0, 0);
    c1 = __builtin_amdgcn_mfma_f32_16x16x32_bf16(A0, B01, c1, 0, 0, 0);
    c1 = __builtin_amdgcn_mfma_f32_16x16x32_bf16(A1, B11, c1, 0, 0, 0);
#pragma unroll
    for (int r = 0; r < 4; ++r) {
      int gq = qbase + qt*16 + rb + r;
      out[(size_t)gq*NO + o0] = fmaxf(c0[r] + b2a, 0.f);
      out[(size_t)gq*NO + o1] = fmaxf(c1[r] + b2b, 0.f);
    }
  }
}

extern "C" void kernel_launch(void* const* d_in, const int* in_sizes, int n_in,
                              void* d_out, int out_size, void* d_ws, size_t ws_size,
                              hipStream_t stream) {
  const float* geom = (const float*)d_in[0];
  const float* lq   = (const float*)d_in[1];
  const int*   nidx = (const int*)d_in[2];
  const int*   rspl = (const int*)d_in[3];
  const float* W1   = (const float*)d_in[4];
  const float* b1   = (const float*)d_in[5];
  const float* W2   = (const float*)d_in[6];
  const float* b2   = (const float*)d_in[7];
  float* out = (float*)d_out;
  int nn = in_sizes[0] / 3;

  char* w = (char*)d_ws;
  float*  feat = (float*)w;                  w += (size_t)QN*12*sizeof(float);   // fallback only
  float4* g4   = (float4*)w;                 w += (size_t)nn * sizeof(float4);
  unsigned short* w2f = (unsigned short*)w;  w += (size_t)16384 * sizeof(unsigned short);
  float* acc   = (float*)w;

  void* args[] = { (void*)&geom, (void*)&lq, (void*)&nidx, (void*)&rspl,
                   (void*)&W1, (void*)&b1, (void*)&W2, (void*)&b2,
                   (void*)&g4, (void*)&w2f, (void*)&acc, (void*)&out, (void*)&nn };
  hipError_t err = hipLaunchCooperativeKernel((void*)fused_kernel, dim3(NBLK),
                                              dim3(256), args, 0, stream);
  if (err != hipSuccess) {
    // deterministic fallback: proven 3-kernel pipeline
    const int padBlocks = (nn + 255) / 256;
    prep_kernel<<<padBlocks + 64, 256, 0, stream>>>(geom, g4, nn, padBlocks, W2, w2f, acc);
    stats_kernel<<<QN/128, 256, 0, stream>>>(g4, lq, nidx, rspl, feat, acc);
    mlp_kernel<<<QN/128, 256, 0, stream>>>(feat, acc, W1, b1, w2f, b2, out);
  }
}

// Round 8
// 143.745 us; speedup vs baseline: 1.7581x; 1.7581x over previous
//
#include <hip/hip_runtime.h>
#include <math.h>

#define QN 131072
#define NF 9
#define NH 64
#define NO 128

using v8s = __attribute__((ext_vector_type(8))) short;
using v4f = __attribute__((ext_vector_type(4))) float;

__device__ __forceinline__ unsigned short f2bf(float x) {
  unsigned u = __float_as_uint(x);
  unsigned r = u + 0x7fffu + ((u >> 16) & 1u);   // RNE
  return (unsigned short)(r >> 16);
}

// ============ K1: pad geom -> float4, build W2 B-fragment table, zero acc ====
__global__ __launch_bounds__(256)
void prep_kernel(const float* __restrict__ geom, float4* __restrict__ g4, int nn,
                 int padBlocks,
                 const float* __restrict__ W2, unsigned short* __restrict__ w2f,
                 float* __restrict__ acc)
{
  const int t = threadIdx.x;
  const int b = blockIdx.x;
  if (b == 0 && t < 2*NF) acc[t] = 0.0f;
  if (b < padBlocks) {
    int i = b * 256 + t;
    if (i < nn) {
      const float* p = geom + (size_t)i * 3;
      g4[i] = make_float4(p[0], p[1], p[2], 0.f);
    }
  } else {
    // B-fragment layout for mfma_f32_16x16x32_bf16:
    // lane l holds B[k' = (l>>4)*8 + j][n = l&15], j=0..7
    int i = (b - padBlocks) * 256 + t;   // [0, 16384)
    int j  = i & 7;
    int l  = (i >> 3) & 63;
    int ot = (i >> 9) & 7;
    int kt = (i >> 12) & 1;
    int row = kt*32 + (l >> 4)*8 + j;
    int col = ot*16 + (l & 15);
    w2f[i] = f2bf(W2[row*NO + col]);
  }
}

// ============ K2: moments (4 thr/query, 8 unguarded upfront gathers) ========
__global__ __launch_bounds__(256)
void stats_kernel(const float4* __restrict__ g4,
                  const float* __restrict__ lq,
                  const int* __restrict__ nidx,
                  const int* __restrict__ rsplit,
                  float* __restrict__ feat,   // [QN][12] (9 used, padded)
                  float* __restrict__ acc)
{
  const int t = threadIdx.x;
  const int j = t & 3;                       // sub-thread within query quad
  const int q = blockIdx.x * 64 + (t >> 2);  // 64 queries per block

  const int s = rsplit[q];
  const int cnt = rsplit[q+1] - s;           // uniform 32 by construction

  // 8 neighbors per sub-thread, unconditional (uniform CSR K=32)
  const int* ip = nidx + s + j*8;
  int4 a0 = *(const int4*)(ip    );
  int4 a1 = *(const int4*)(ip + 4);

  const float qx = lq[q*3+0], qy = lq[q*3+1], qz = lq[q*3+2];

  int ids[8] = {a0.x,a0.y,a0.z,a0.w, a1.x,a1.y,a1.z,a1.w};
  float4 P[8];
#pragma unroll
  for (int m = 0; m < 8; ++m) P[m] = g4[ids[m]];

  float sx=0.f, sy=0.f, sz=0.f;
  float sxx=0.f, sxy=0.f, sxz=0.f, syy=0.f, syz=0.f, szz=0.f;
  float sd=0.f, sd2=0.f;
#pragma unroll
  for (int m = 0; m < 8; ++m) {
    float4 p = P[m];
    sx += p.x; sy += p.y; sz += p.z;
    sxx = fmaf(p.x,p.x,sxx); sxy = fmaf(p.x,p.y,sxy); sxz = fmaf(p.x,p.z,sxz);
    syy = fmaf(p.y,p.y,syy); syz = fmaf(p.y,p.z,syz); szz = fmaf(p.z,p.z,szz);
    float dx = p.x-qx, dy = p.y-qy, dz = p.z-qz;
    float dd = fmaf(dx,dx,fmaf(dy,dy,dz*dz));
    sd2 += dd;
    sd += sqrtf(dd);
  }

  // quad reduce (masks 1,2 — stay inside the query's 4 lanes)
#pragma unroll
  for (int msk = 1; msk < 4; msk <<= 1) {
    sx  += __shfl_xor(sx,  msk);
    sy  += __shfl_xor(sy,  msk);
    sz  += __shfl_xor(sz,  msk);
    sxx += __shfl_xor(sxx, msk);
    sxy += __shfl_xor(sxy, msk);
    sxz += __shfl_xor(sxz, msk);
    syy += __shfl_xor(syy, msk);
    syz += __shfl_xor(syz, msk);
    szz += __shfl_xor(szz, msk);
    sd  += __shfl_xor(sd,  msk);
    sd2 += __shfl_xor(sd2, msk);
  }
  // all 4 sub-lanes now hold identical full sums

  float cntf = (float)cnt;
  float denom = fmaxf(cntf, 1.0f);
  float inv = 1.0f / denom;
  float Davg = sd * inv;
  float Dvar = fmaxf(sd2 * inv - Davg*Davg, 0.0f);
  float cx = sx*inv, cy = sy*inv, cz = sz*inv;

  float a00 = sxx*inv - cx*cx;
  float a01 = sxy*inv - cx*cy;
  float a02 = sxz*inv - cx*cz;
  float a11 = syy*inv - cy*cy;
  float a12 = syz*inv - cy*cz;
  float a22 = szz*inv - cz*cz;

  float l0, l1, l2;
  {
    float p1 = a01*a01 + a02*a02 + a12*a12;
    float qm = (a00 + a11 + a22) * (1.0f/3.0f);
    float b00 = a00 - qm, b11 = a11 - qm, b22 = a22 - qm;
    float p2 = b00*b00 + b11*b11 + b22*b22 + 2.0f*p1;
    if (p2 < 1e-12f) {
      l0 = l1 = l2 = qm;
    } else {
      float p = sqrtf(p2 * (1.0f/6.0f));
      float ip2 = 1.0f / p;
      float c00 = b00*ip2, c11 = b11*ip2, c22 = b22*ip2;
      float c01 = a01*ip2, c02 = a02*ip2, c12 = a12*ip2;
      float det = c00*(c11*c22 - c12*c12)
                - c01*(c01*c22 - c12*c02)
                + c02*(c01*c12 - c11*c02);
      float r = fminf(1.0f, fmaxf(-1.0f, 0.5f*det));
      float phi = acosf(r) * (1.0f/3.0f);
      float tp = 2.0f * p;
      l0 = qm + tp * __cosf(phi);
      l2 = qm + tp * __cosf(phi + 2.0943951023931953f);
      l1 = 3.0f*qm - l0 - l2;
    }
  }

  float ft[NF];
  if (cntf > 0.f) {
    ft[0] = cntf; ft[1] = Davg; ft[2] = Dvar;
    ft[3] = cx - qx; ft[4] = cy - qy; ft[5] = cz - qz;
    ft[6] = l0; ft[7] = l1; ft[8] = l2;
  } else {
#pragma unroll
    for (int f = 0; f < NF; ++f) ft[f] = 0.f;
  }

  if (j == 0) {
    float* fp = feat + (size_t)q * 12;
    *(float4*)(fp    ) = make_float4(ft[0], ft[1], ft[2], ft[3]);
    *(float4*)(fp + 4) = make_float4(ft[4], ft[5], ft[6], ft[7]);
    *(float4*)(fp + 8) = make_float4(ft[8], 0.f, 0.f, 0.f);
  }

  // global mean/var accumulation, fp32.
  // Lanes ≡0 (mod 4) hold the wave's 16 distinct queries; the xor-orbit of
  // lane 0 under masks {4,8,16,32} is exactly those lanes -> each query
  // counted once.
  __shared__ float sacc[4][2*NF];
  const int wid = t >> 6, lane = t & 63;
#pragma unroll
  for (int f = 0; f < NF; ++f) {
    float s1 = ft[f];
    float s2 = ft[f]*ft[f];
#pragma unroll
    for (int msk = 4; msk < 64; msk <<= 1) {
      s1 += __shfl_xor(s1, msk);
      s2 += __shfl_xor(s2, msk);
    }
    if (lane == 0) { sacc[wid][f] = s1; sacc[wid][NF+f] = s2; }
  }
  __syncthreads();
  if (t < 2*NF) {
    float ssum = sacc[0][t] + sacc[1][t] + sacc[2][t] + sacc[3][t];
    atomicAdd(&acc[t], ssum);
  }
}

// ============ K3: fused finalize + MLP (phase1 VALU fp32, phase2 MFMA bf16) ==
__global__ __launch_bounds__(256)
void mlp_kernel(const float* __restrict__ feat,
                const float* __restrict__ acc,
                const float* __restrict__ W1, const float* __restrict__ b1,
                const unsigned short* __restrict__ w2f,
                const float* __restrict__ b2,
                float* __restrict__ out)
{
  __shared__ float sW1[NF*NH];
  __shared__ float sb1[NH];
  __shared__ float sb2[NO];
  __shared__ float ssc[NF], sbi[NF];
  __shared__ __align__(16) unsigned short ldsA[8*2*64*8];  // [qt][kt][lane][j] bf16
  __shared__ __align__(16) unsigned short ldsB[2*8*64*8];  // [kt][ot][lane][j] bf16

  const int t = threadIdx.x;
  const int qbase = blockIdx.x * 128;

  for (int i = t; i < NF*NH; i += 256) sW1[i] = W1[i];
  if (t < NH) sb1[t] = b1[t];
  if (t >= 64 && t < 64+NO) sb2[t-64] = b2[t-64];
  for (int i = t; i < 4096; i += 256) ((uint*)ldsB)[i] = ((const uint*)w2f)[i];
  if (t >= 192 && t < 192+NF) {
    int f = t - 192;
    double s = (double)acc[f], s2 = (double)acc[NF+f];
    const double Qd = (double)QN;
    double mean = s / Qd;
    double var = fmax((s2 - s*s/Qd) / (Qd - 1.0), 0.0);
    double sd = sqrt(var);
    if (sd < 1e-6) sd = 1.0;
    double iscl = 1.0 / sd;
    ssc[f] = (float)iscl;
    sbi[f] = (float)(-mean * iscl);
  }
  __syncthreads();

  // phase 1: h = relu(feat@W1+b1) -> A-fragment order in ldsA
#pragma unroll
  for (int pass = 0; pass < 4; ++pass) {
    int item = pass*256 + t;
    int q  = item & 127;
    int kc = item >> 7;
    const float* fp = feat + (size_t)(qbase + q) * 12;
    float4 f0 = *(const float4*)(fp);
    float4 f1 = *(const float4*)(fp + 4);
    float f8v = fp[8];
    float fv[NF];
    fv[0] = fmaf(f0.x, ssc[0], sbi[0]);
    fv[1] = fmaf(f0.y, ssc[1], sbi[1]);
    fv[2] = fmaf(f0.z, ssc[2], sbi[2]);
    fv[3] = fmaf(f0.w, ssc[3], sbi[3]);
    fv[4] = fmaf(f1.x, ssc[4], sbi[4]);
    fv[5] = fmaf(f1.y, ssc[5], sbi[5]);
    fv[6] = fmaf(f1.z, ssc[6], sbi[6]);
    fv[7] = fmaf(f1.w, ssc[7], sbi[7]);
    fv[8] = fmaf(f8v,  ssc[8], sbi[8]);

    float h[8];
#pragma unroll
    for (int jj = 0; jj < 8; ++jj) h[jj] = sb1[kc*8 + jj];
#pragma unroll
    for (int k = 0; k < NF; ++k) {
      float fk = fv[k];
#pragma unroll
      for (int jj = 0; jj < 8; ++jj)
        h[jj] = fmaf(fk, sW1[k*NH + kc*8 + jj], h[jj]);
    }
    uint pk[4];
#pragma unroll
    for (int jj = 0; jj < 4; ++jj) {
      uint lo = f2bf(fmaxf(h[2*jj  ], 0.f));
      uint hi = f2bf(fmaxf(h[2*jj+1], 0.f));
      pk[jj] = lo | (hi << 16);
    }
    int base = ((((q >> 4)*2 + (kc >> 2))*64) + (q & 15) + 16*(kc & 3)) * 8;
    *(uint4*)&ldsA[base] = make_uint4(pk[0], pk[1], pk[2], pk[3]);
  }
  __syncthreads();

  // phase 2: out = relu(h@W2+b2) via mfma_f32_16x16x32_bf16
  const int wave = t >> 6;
  const int lane = t & 63;
  const int col  = lane & 15;
  const int rb   = (lane >> 4) * 4;

  v8s B00 = *(v8s*)&ldsB[(((0*8) + 2*wave    )*64 + lane)*8];
  v8s B01 = *(v8s*)&ldsB[(((0*8) + 2*wave + 1)*64 + lane)*8];
  v8s B10 = *(v8s*)&ldsB[(((1*8) + 2*wave    )*64 + lane)*8];
  v8s B11 = *(v8s*)&ldsB[(((1*8) + 2*wave + 1)*64 + lane)*8];

  const int o0 = (2*wave    )*16 + col;
  const int o1 = (2*wave + 1)*16 + col;
  const float b2a = sb2[o0];
  const float b2b = sb2[o1];

#pragma unroll
  for (int qt = 0; qt < 8; ++qt) {
    v8s A0 = *(v8s*)&ldsA[((qt*2 + 0)*64 + lane)*8];
    v8s A1 = *(v8s*)&ldsA[((qt*2 + 1)*64 + lane)*8];
    v4f c0 = {0.f, 0.f, 0.f, 0.f};
    v4f c1 = {0.f, 0.f, 0.f, 0.f};
    c0 = __builtin_amdgcn_mfma_f32_16x16x32_bf16(A0, B00, c0, 0, 0, 0);
    c0 = __builtin_amdgcn_mfma_f32_16x16x32_bf16(A1, B10, c0, 0, 0, 0);
    c1 = __builtin_amdgcn_mfma_f32_16x16x32_bf16(A0, B01, c1, 0, 0, 0);
    c1 = __builtin_amdgcn_mfma_f32_16x16x32_bf16(A1, B11, c1, 0, 0, 0);
#pragma unroll
    for (int r = 0; r < 4; ++r) {
      int gq = qbase + qt*16 + rb + r;
      out[(size_t)gq*NO + o0] = fmaxf(c0[r] + b2a, 0.f);
      out[(size_t)gq*NO + o1] = fmaxf(c1[r] + b2b, 0.f);
    }
  }
}

extern "C" void kernel_launch(void* const* d_in, const int* in_sizes, int n_in,
                              void* d_out, int out_size, void* d_ws, size_t ws_size,
                              hipStream_t stream) {
  const float* geom = (const float*)d_in[0];
  const float* lq   = (const float*)d_in[1];
  const int*   nidx = (const int*)d_in[2];
  const int*   rspl = (const int*)d_in[3];
  const float* W1   = (const float*)d_in[4];
  const float* b1   = (const float*)d_in[5];
  const float* W2   = (const float*)d_in[6];
  const float* b2   = (const float*)d_in[7];
  float* out = (float*)d_out;
  const int nn = in_sizes[0] / 3;

  // ws layout (16B-aligned chunks)
  char* w = (char*)d_ws;
  float*  feat = (float*)w;                  w += (size_t)QN*12*sizeof(float);      // 6.3 MB
  float4* g4   = (float4*)w;                 w += (size_t)nn*sizeof(float4);        // 3.2 MB
  unsigned short* w2f = (unsigned short*)w;  w += 16384*sizeof(unsigned short);     // 32 KB
  float* acc   = (float*)w;

  const int padBlocks = (nn + 255) / 256;
  prep_kernel<<<padBlocks + 64, 256, 0, stream>>>(geom, g4, nn, padBlocks, W2, w2f, acc);
  stats_kernel<<<QN/64, 256, 0, stream>>>(g4, lq, nidx, rspl, feat, acc);
  mlp_kernel<<<QN/128, 256, 0, stream>>>(feat, acc, W1, b1, w2f, b2, out);
}

// Round 9
// 133.931 us; speedup vs baseline: 1.8869x; 1.0733x over previous
//
#include <hip/hip_runtime.h>
#include <math.h>

#define QN 131072
#define NF 9
#define NH 64
#define NO 128

using v8s = __attribute__((ext_vector_type(8))) short;
using v4f = __attribute__((ext_vector_type(4))) float;

__device__ __forceinline__ unsigned short f2bf(float x) {
  unsigned u = __float_as_uint(x);
  unsigned r = u + 0x7fffu + ((u >> 16) & 1u);   // RNE
  return (unsigned short)(r >> 16);
}

// ============ K1: pad geom -> float4, build W2 B-fragment table, zero acc ====
__global__ __launch_bounds__(256)
void prep_kernel(const float* __restrict__ geom, float4* __restrict__ g4, int nn,
                 int padBlocks,
                 const float* __restrict__ W2, unsigned short* __restrict__ w2f,
                 float* __restrict__ acc)
{
  const int t = threadIdx.x;
  const int b = blockIdx.x;
  if (b == 0 && t < 2*NF) acc[t] = 0.0f;
  if (b < padBlocks) {
    int i = b * 256 + t;
    if (i < nn) {
      const float* p = geom + (size_t)i * 3;
      g4[i] = make_float4(p[0], p[1], p[2], 0.f);
    }
  } else {
    // B-fragment layout for mfma_f32_16x16x32_bf16:
    // lane l holds B[k' = (l>>4)*8 + j][n = l&15], j=0..7
    int i = (b - padBlocks) * 256 + t;   // [0, 16384)
    int j  = i & 7;
    int l  = (i >> 3) & 63;
    int ot = (i >> 9) & 7;
    int kt = (i >> 12) & 1;
    int row = kt*32 + (l >> 4)*8 + j;
    int col = ot*16 + (l & 15);
    w2f[i] = f2bf(W2[row*NO + col]);
  }
}

// ============ K2: moments — 2 thr/query, 16 forced-resident gathers =========
__global__ __launch_bounds__(256)
void stats_kernel(const float4* __restrict__ g4,
                  const float* __restrict__ lq,
                  const int* __restrict__ nidx,
                  const int* __restrict__ rsplit,
                  float* __restrict__ feat,   // [QN][12] (9 used, padded)
                  float* __restrict__ acc)
{
  const int t = threadIdx.x;
  const int j = t & 1;                       // sub-thread within query pair
  const int q = blockIdx.x * 128 + (t >> 1); // 128 queries per block

  const int s = rsplit[q];
  const int cnt = rsplit[q+1] - s;           // uniform 32 by construction

  // 16 neighbors per sub-thread, unconditional (uniform CSR K=32)
  const int* ip = nidx + s + j*16;
  int4 a0 = *(const int4*)(ip     );
  int4 a1 = *(const int4*)(ip +  4);
  int4 a2 = *(const int4*)(ip +  8);
  int4 a3 = *(const int4*)(ip + 12);

  const float qx = lq[q*3+0], qy = lq[q*3+1], qz = lq[q*3+2];

  int idsA[8] = {a0.x,a0.y,a0.z,a0.w, a1.x,a1.y,a1.z,a1.w};
  int idsB[8] = {a2.x,a2.y,a2.z,a2.w, a3.x,a3.y,a3.z,a3.w};

  // force all 16 gathers in flight before any accumulation (distinct arrays)
  float4 PA[8], PB[8];
#pragma unroll
  for (int m = 0; m < 8; ++m) PA[m] = g4[idsA[m]];
#pragma unroll
  for (int m = 0; m < 8; ++m) PB[m] = g4[idsB[m]];

  float sx=0.f, sy=0.f, sz=0.f;
  float sxx=0.f, sxy=0.f, sxz=0.f, syy=0.f, syz=0.f, szz=0.f;
  float sd=0.f, sd2=0.f;
#pragma unroll
  for (int m = 0; m < 8; ++m) {
    float4 p = PA[m];
    sx += p.x; sy += p.y; sz += p.z;
    sxx = fmaf(p.x,p.x,sxx); sxy = fmaf(p.x,p.y,sxy); sxz = fmaf(p.x,p.z,sxz);
    syy = fmaf(p.y,p.y,syy); syz = fmaf(p.y,p.z,syz); szz = fmaf(p.z,p.z,szz);
    float dx = p.x-qx, dy = p.y-qy, dz = p.z-qz;
    float dd = fmaf(dx,dx,fmaf(dy,dy,dz*dz));
    sd2 += dd;
    sd += sqrtf(dd);
  }
#pragma unroll
  for (int m = 0; m < 8; ++m) {
    float4 p = PB[m];
    sx += p.x; sy += p.y; sz += p.z;
    sxx = fmaf(p.x,p.x,sxx); sxy = fmaf(p.x,p.y,sxy); sxz = fmaf(p.x,p.z,sxz);
    syy = fmaf(p.y,p.y,syy); syz = fmaf(p.y,p.z,syz); szz = fmaf(p.z,p.z,szz);
    float dx = p.x-qx, dy = p.y-qy, dz = p.z-qz;
    float dd = fmaf(dx,dx,fmaf(dy,dy,dz*dz));
    sd2 += dd;
    sd += sqrtf(dd);
  }

  // pair reduce (mask 1)
  sx  += __shfl_xor(sx,  1);
  sy  += __shfl_xor(sy,  1);
  sz  += __shfl_xor(sz,  1);
  sxx += __shfl_xor(sxx, 1);
  sxy += __shfl_xor(sxy, 1);
  sxz += __shfl_xor(sxz, 1);
  syy += __shfl_xor(syy, 1);
  syz += __shfl_xor(syz, 1);
  szz += __shfl_xor(szz, 1);
  sd  += __shfl_xor(sd,  1);
  sd2 += __shfl_xor(sd2, 1);
  // both lanes of the pair now hold full sums

  float cntf = (float)cnt;
  float denom = fmaxf(cntf, 1.0f);
  float inv = 1.0f / denom;
  float Davg = sd * inv;
  float Dvar = fmaxf(sd2 * inv - Davg*Davg, 0.0f);
  float cx = sx*inv, cy = sy*inv, cz = sz*inv;

  float a00 = sxx*inv - cx*cx;
  float a01 = sxy*inv - cx*cy;
  float a02 = sxz*inv - cx*cz;
  float a11 = syy*inv - cy*cy;
  float a12 = syz*inv - cy*cz;
  float a22 = szz*inv - cz*cz;

  float l0, l1, l2;
  {
    float p1 = a01*a01 + a02*a02 + a12*a12;
    float qm = (a00 + a11 + a22) * (1.0f/3.0f);
    float b00 = a00 - qm, b11 = a11 - qm, b22 = a22 - qm;
    float p2 = b00*b00 + b11*b11 + b22*b22 + 2.0f*p1;
    if (p2 < 1e-12f) {
      l0 = l1 = l2 = qm;
    } else {
      float p = sqrtf(p2 * (1.0f/6.0f));
      float ip2 = 1.0f / p;
      float c00 = b00*ip2, c11 = b11*ip2, c22 = b22*ip2;
      float c01 = a01*ip2, c02 = a02*ip2, c12 = a12*ip2;
      float det = c00*(c11*c22 - c12*c12)
                - c01*(c01*c22 - c12*c02)
                + c02*(c01*c12 - c11*c02);
      float r = fminf(1.0f, fmaxf(-1.0f, 0.5f*det));
      float phi = acosf(r) * (1.0f/3.0f);
      float tp = 2.0f * p;
      l0 = qm + tp * __cosf(phi);
      l2 = qm + tp * __cosf(phi + 2.0943951023931953f);
      l1 = 3.0f*qm - l0 - l2;
    }
  }

  float ft[NF];
  if (cntf > 0.f) {
    ft[0] = cntf; ft[1] = Davg; ft[2] = Dvar;
    ft[3] = cx - qx; ft[4] = cy - qy; ft[5] = cz - qz;
    ft[6] = l0; ft[7] = l1; ft[8] = l2;
  } else {
#pragma unroll
    for (int f = 0; f < NF; ++f) ft[f] = 0.f;
  }

  if (j == 0) {
    float* fp = feat + (size_t)q * 12;
    *(float4*)(fp    ) = make_float4(ft[0], ft[1], ft[2], ft[3]);
    *(float4*)(fp + 4) = make_float4(ft[4], ft[5], ft[6], ft[7]);
    *(float4*)(fp + 8) = make_float4(ft[8], 0.f, 0.f, 0.f);
  }

  // global mean/var accumulation, fp32.
  // Even lanes hold the wave's 32 distinct queries; the xor-orbit of lane 0
  // under masks {2,4,8,16,32} is exactly the even lanes -> each query
  // counted once.
  __shared__ float sacc[4][2*NF];
  const int wid = t >> 6, lane = t & 63;
#pragma unroll
  for (int f = 0; f < NF; ++f) {
    float s1 = ft[f];
    float s2 = ft[f]*ft[f];
#pragma unroll
    for (int msk = 2; msk < 64; msk <<= 1) {
      s1 += __shfl_xor(s1, msk);
      s2 += __shfl_xor(s2, msk);
    }
    if (lane == 0) { sacc[wid][f] = s1; sacc[wid][NF+f] = s2; }
  }
  __syncthreads();
  if (t < 2*NF) {
    float ssum = sacc[0][t] + sacc[1][t] + sacc[2][t] + sacc[3][t];
    atomicAdd(&acc[t], ssum);
  }
}

// ============ K3: fused finalize + MLP (phase1 VALU fp32, phase2 MFMA bf16) ==
__global__ __launch_bounds__(256)
void mlp_kernel(const float* __restrict__ feat,
                const float* __restrict__ acc,
                const float* __restrict__ W1, const float* __restrict__ b1,
                const unsigned short* __restrict__ w2f,
                const float* __restrict__ b2,
                float* __restrict__ out)
{
  __shared__ float sW1[NF*NH];
  __shared__ float sb1[NH];
  __shared__ float sb2[NO];
  __shared__ float ssc[NF], sbi[NF];
  __shared__ __align__(16) unsigned short ldsA[8*2*64*8];  // [qt][kt][lane][j] bf16
  __shared__ __align__(16) unsigned short ldsB[2*8*64*8];  // [kt][ot][lane][j] bf16

  const int t = threadIdx.x;
  const int qbase = blockIdx.x * 128;

  for (int i = t; i < NF*NH; i += 256) sW1[i] = W1[i];
  if (t < NH) sb1[t] = b1[t];
  if (t >= 64 && t < 64+NO) sb2[t-64] = b2[t-64];
  for (int i = t; i < 4096; i += 256) ((uint*)ldsB)[i] = ((const uint*)w2f)[i];
  if (t >= 192 && t < 192+NF) {
    int f = t - 192;
    double s = (double)acc[f], s2 = (double)acc[NF+f];
    const double Qd = (double)QN;
    double mean = s / Qd;
    double var = fmax((s2 - s*s/Qd) / (Qd - 1.0), 0.0);
    double sd = sqrt(var);
    if (sd < 1e-6) sd = 1.0;
    double iscl = 1.0 / sd;
    ssc[f] = (float)iscl;
    sbi[f] = (float)(-mean * iscl);
  }
  __syncthreads();

  // phase 1: h = relu(feat@W1+b1) -> A-fragment order in ldsA
#pragma unroll
  for (int pass = 0; pass < 4; ++pass) {
    int item = pass*256 + t;
    int q  = item & 127;
    int kc = item >> 7;
    const float* fp = feat + (size_t)(qbase + q) * 12;
    float4 f0 = *(const float4*)(fp);
    float4 f1 = *(const float4*)(fp + 4);
    float f8v = fp[8];
    float fv[NF];
    fv[0] = fmaf(f0.x, ssc[0], sbi[0]);
    fv[1] = fmaf(f0.y, ssc[1], sbi[1]);
    fv[2] = fmaf(f0.z, ssc[2], sbi[2]);
    fv[3] = fmaf(f0.w, ssc[3], sbi[3]);
    fv[4] = fmaf(f1.x, ssc[4], sbi[4]);
    fv[5] = fmaf(f1.y, ssc[5], sbi[5]);
    fv[6] = fmaf(f1.z, ssc[6], sbi[6]);
    fv[7] = fmaf(f1.w, ssc[7], sbi[7]);
    fv[8] = fmaf(f8v,  ssc[8], sbi[8]);

    float h[8];
#pragma unroll
    for (int jj = 0; jj < 8; ++jj) h[jj] = sb1[kc*8 + jj];
#pragma unroll
    for (int k = 0; k < NF; ++k) {
      float fk = fv[k];
#pragma unroll
      for (int jj = 0; jj < 8; ++jj)
        h[jj] = fmaf(fk, sW1[k*NH + kc*8 + jj], h[jj]);
    }
    uint pk[4];
#pragma unroll
    for (int jj = 0; jj < 4; ++jj) {
      uint lo = f2bf(fmaxf(h[2*jj  ], 0.f));
      uint hi = f2bf(fmaxf(h[2*jj+1], 0.f));
      pk[jj] = lo | (hi << 16);
    }
    int base = ((((q >> 4)*2 + (kc >> 2))*64) + (q & 15) + 16*(kc & 3)) * 8;
    *(uint4*)&ldsA[base] = make_uint4(pk[0], pk[1], pk[2], pk[3]);
  }
  __syncthreads();

  // phase 2: out = relu(h@W2+b2) via mfma_f32_16x16x32_bf16
  const int wave = t >> 6;
  const int lane = t & 63;
  const int col  = lane & 15;
  const int rb   = (lane >> 4) * 4;

  v8s B00 = *(v8s*)&ldsB[(((0*8) + 2*wave    )*64 + lane)*8];
  v8s B01 = *(v8s*)&ldsB[(((0*8) + 2*wave + 1)*64 + lane)*8];
  v8s B10 = *(v8s*)&ldsB[(((1*8) + 2*wave    )*64 + lane)*8];
  v8s B11 = *(v8s*)&ldsB[(((1*8) + 2*wave + 1)*64 + lane)*8];

  const int o0 = (2*wave    )*16 + col;
  const int o1 = (2*wave + 1)*16 + col;
  const float b2a = sb2[o0];
  const float b2b = sb2[o1];

#pragma unroll
  for (int qt = 0; qt < 8; ++qt) {
    v8s A0 = *(v8s*)&ldsA[((qt*2 + 0)*64 + lane)*8];
    v8s A1 = *(v8s*)&ldsA[((qt*2 + 1)*64 + lane)*8];
    v4f c0 = {0.f, 0.f, 0.f, 0.f};
    v4f c1 = {0.f, 0.f, 0.f, 0.f};
    c0 = __builtin_amdgcn_mfma_f32_16x16x32_bf16(A0, B00, c0, 0, 0, 0);
    c0 = __builtin_amdgcn_mfma_f32_16x16x32_bf16(A1, B10, c0, 0, 0, 0);
    c1 = __builtin_amdgcn_mfma_f32_16x16x32_bf16(A0, B01, c1, 0, 0, 0);
    c1 = __builtin_amdgcn_mfma_f32_16x16x32_bf16(A1, B11, c1, 0, 0, 0);
#pragma unroll
    for (int r = 0; r < 4; ++r) {
      int gq = qbase + qt*16 + rb + r;
      out[(size_t)gq*NO + o0] = fmaxf(c0[r] + b2a, 0.f);
      out[(size_t)gq*NO + o1] = fmaxf(c1[r] + b2b, 0.f);
    }
  }
}

extern "C" void kernel_launch(void* const* d_in, const int* in_sizes, int n_in,
                              void* d_out, int out_size, void* d_ws, size_t ws_size,
                              hipStream_t stream) {
  const float* geom = (const float*)d_in[0];
  const float* lq   = (const float*)d_in[1];
  const int*   nidx = (const int*)d_in[2];
  const int*   rspl = (const int*)d_in[3];
  const float* W1   = (const float*)d_in[4];
  const float* b1   = (const float*)d_in[5];
  const float* W2   = (const float*)d_in[6];
  const float* b2   = (const float*)d_in[7];
  float* out = (float*)d_out;
  const int nn = in_sizes[0] / 3;

  // ws layout (16B-aligned chunks)
  char* w = (char*)d_ws;
  float*  feat = (float*)w;                  w += (size_t)QN*12*sizeof(float);      // 6.3 MB
  float4* g4   = (float4*)w;                 w += (size_t)nn*sizeof(float4);        // 3.2 MB
  unsigned short* w2f = (unsigned short*)w;  w += 16384*sizeof(unsigned short);     // 32 KB
  float* acc   = (float*)w;

  const int padBlocks = (nn + 255) / 256;
  prep_kernel<<<padBlocks + 64, 256, 0, stream>>>(geom, g4, nn, padBlocks, W2, w2f, acc);
  stats_kernel<<<QN/128, 256, 0, stream>>>(g4, lq, nidx, rspl, feat, acc);
  mlp_kernel<<<QN/128, 256, 0, stream>>>(feat, acc, W1, b1, w2f, b2, out);
}